// Round 1
// baseline (139.110 us; speedup 1.0000x reference)
//
#include <hip/hip_runtime.h>

#define EPSILON 0.05f
#define NW   4096          // persistent waves in fused kernel (1024 blocks x 4 waves)
#define NBLK (NW / 4)      // 1024 blocks; partials are per-block now

typedef float v4f __attribute__((ext_vector_type(4)));

// Fused persistent kernel (S=1024).
// Phase A: lane j (j < rpw=4) owns ray (wave + j*NW); ONLY masked lanes run the
//   dual search. Search = 5-probe binary search over the 32 line-heads z[32m]
//   (chain depth 5) + one parallel 8xv4f scan of the boundary line (chain 1),
//   vs the old 10-deep dependent chain. Exact same counts -> deterministic.
// Phase B: loop over the wave's rays in pairs; bounds/mask come from
//   v_readlane (registers). steps = fm ? ceil(upper/256) : 0, so unmasked
//   rays issue ZERO weight loads. Per-wave partials are reduced across the
//   block's 4 waves in LDS -> one (e,n,m) triple per block, no atomics.
__global__ __launch_bounds__(256, 4) void sight_fused_1024(
    const float* __restrict__ ray_depth,   // [N]
    const float* __restrict__ z_vals,      // [N, 1024] sorted rows
    const float* __restrict__ weights,     // [N, 1024]
    const int*   __restrict__ ray_mask,    // [N]
    float* __restrict__ partials,          // [3*NBLK]
    int n_rays)
{
    const int lane = threadIdx.x & 63;
    const int wv   = threadIdx.x >> 6;                 // wave in block, 0..3
    const int wave = (int)(blockIdx.x * 4 + wv);       // 0..NW-1
    const int rpw  = (n_rays + NW - 1) / NW;           // rays per wave (<=64)

    // ---- Phase A: mask-gated per-lane dual search (5 probes + line scan) ----
    const int  rj  = wave + lane * NW;
    const bool vld = (lane < rpw) && (rj < n_rays);
    const int  rc  = vld ? rj : 0;
    const int  mk  = vld ? ray_mask[rc] : 0;

    int mypk = 0;
    if (mk != 0) {                      // divergent; inactive lanes issue no loads
        const float d  = ray_depth[rc];
        const float lo = d - EPSILON;
        const float hi = d + EPSILON;
        const float* zr = z_vals + (size_t)rc * 1024;

        // binary search over line-heads z[32*m], m in [0,32): l = #heads < bound
        int l1 = 0, h1 = 32, l2 = 0, h2 = 32;
        #pragma unroll
        for (int it = 0; it < 5; ++it) {
            const int m1 = (l1 + h1) >> 1;
            const int m2 = (l2 + h2) >> 1;
            const float a = zr[m1 << 5];
            const float b = zr[m2 << 5];
            if (a < lo) l1 = m1 + 1; else h1 = m1;
            if (b < hi) l2 = m2 + 1; else h2 = m2;
        }
        // scan the 32-float line containing each boundary (8 parallel v4f each)
        const int base1 = (l1 - 1) << 5;        // valid only when l1 > 0
        const int base2 = (l2 - 1) << 5;
        const v4f* z4a = (const v4f*)(zr + (l1 ? base1 : 0));
        const v4f* z4b = (const v4f*)(zr + (l2 ? base2 : 0));
        v4f q1[8], q2[8];
        #pragma unroll
        for (int t = 0; t < 8; ++t) { q1[t] = z4a[t]; q2[t] = z4b[t]; }
        int c1 = 0, c2 = 0;
        #pragma unroll
        for (int t = 0; t < 8; ++t) {
            #pragma unroll
            for (int c = 0; c < 4; ++c) {
                c1 += (q1[t][c] < lo) ? 1 : 0;
                c2 += (q2[t][c] < hi) ? 1 : 0;
            }
        }
        const int lower = l1 ? (base1 + c1) : 0;
        const int upper = l2 ? (base2 + c2) : 0;
        mypk = (int)((unsigned)lower | ((unsigned)upper << 16) | 0x80000000u);
    }

    // ---- Phase B: stream weights (masked rays only), ray pairs ----
    float e_lane = 0.0f;   // sum fm * w^2 over [0, lower)
    float n_acc  = 0.0f;   // sum fm * (1 - w_near)^2   (lane-uniform)
    float m_acc  = 0.0f;   // sum fm                    (lane-uniform)

    for (int i = 0; i < rpw; i += 2) {
        const int pkA = __builtin_amdgcn_readlane(mypk, i);
        const int pkB = (i + 1 < rpw) ? __builtin_amdgcn_readlane(mypk, i + 1) : 0;

        const int   lowA = pkA & 0xffff,          lowB = pkB & 0xffff;
        const int   upA  = (pkA >> 16) & 0x7fff,  upB  = (pkB >> 16) & 0x7fff;
        const bool  mA   = ((unsigned)pkA >> 31) != 0;
        const bool  mB   = ((unsigned)pkB >> 31) != 0;
        const float fmA  = mA ? 1.0f : 0.0f;
        const float fmB  = mB ? 1.0f : 0.0f;
        const int   stA  = mA ? ((upA + 255) >> 8) : 0;   // chunks (0..4)
        const int   stB  = mB ? ((upB + 255) >> 8) : 0;

        const v4f* wA = (const v4f*)(weights + (size_t)(wave + (size_t)i * NW) * 1024);
        const v4f* wB = (const v4f*)(weights + (size_t)(wave + (size_t)(i + 1) * NW) * 1024);

        v4f a[4], b[4];
        #pragma unroll
        for (int s = 0; s < 4; ++s)
            a[s] = (s < stA) ? wA[lane + 64 * s] : (v4f){0.0f, 0.0f, 0.0f, 0.0f};
        #pragma unroll
        for (int s = 0; s < 4; ++s)
            b[s] = (s < stB) ? wB[lane + 64 * s] : (v4f){0.0f, 0.0f, 0.0f, 0.0f};

        float eA = 0.0f, wnA = 0.0f, eB = 0.0f, wnB = 0.0f;
        #pragma unroll
        for (int s = 0; s < 4; ++s) {
            #pragma unroll
            for (int c = 0; c < 4; ++c) {
                const int   j  = 256 * s + 4 * lane + c;
                const float wa = a[s][c];
                const float wb = b[s][c];
                eA  += (j < lowA) ? wa * wa : 0.0f;
                wnA += (j >= lowA && j < upA) ? wa : 0.0f;
                eB  += (j < lowB) ? wb * wb : 0.0f;
                wnB += (j >= lowB && j < upB) ? wb : 0.0f;
            }
        }
        #pragma unroll
        for (int off = 32; off > 0; off >>= 1) {
            wnA += __shfl_xor(wnA, off, 64);
            wnB += __shfl_xor(wnB, off, 64);
        }
        const float tA = 1.0f - wnA, tB = 1.0f - wnB;
        e_lane += fmA * eA + fmB * eB;
        n_acc  += fmA * tA * tA + fmB * tB * tB;
        m_acc  += fmA + fmB;
    }

    #pragma unroll
    for (int off = 32; off > 0; off >>= 1) e_lane += __shfl_xor(e_lane, off, 64);

    // ---- block-level reduction: 4 waves -> one triple per block ----
    __shared__ float red[4][3];
    if (lane == 0) {
        red[wv][0] = e_lane;
        red[wv][1] = n_acc;
        red[wv][2] = m_acc;
    }
    __syncthreads();
    if (threadIdx.x == 0) {
        const float e = red[0][0] + red[1][0] + red[2][0] + red[3][0];
        const float n = red[0][1] + red[1][1] + red[2][1] + red[3][1];
        const float m = red[0][2] + red[1][2] + red[2][2] + red[3][2];
        partials[blockIdx.x]            = e;
        partials[NBLK + blockIdx.x]     = n;
        partials[2 * NBLK + blockIdx.x] = m;
    }
}

// Generic fallback (runtime S): full elementwise pass, atomics into the
// same [3*NBLK] partials (launcher memsets on this path).
__global__ __launch_bounds__(256) void sight_near_loss_generic(
    const float* __restrict__ ray_depth,
    const float* __restrict__ z_vals,
    const float* __restrict__ weights,
    const int*   __restrict__ ray_mask,
    float* __restrict__ partials,
    int n_rays, int S)
{
    const int wv = threadIdx.x >> 6;
    const int lane = threadIdx.x & 63;
    const int r = blockIdx.x * 4 + wv;
    if (r >= n_rays) return;

    const float d  = ray_depth[r];
    const float lo = d - EPSILON;
    const float hi = d + EPSILON;

    float empty = 0.0f, wnear = 0.0f;
    const float* zr = z_vals  + (size_t)r * S;
    const float* wr = weights + (size_t)r * S;
    for (int k = lane; k < S; k += 64) {
        const float z = zr[k];
        const float w = wr[k];
        empty += (z < lo) ? w * w : 0.0f;
        wnear += (z >= lo && z < hi) ? w : 0.0f;
    }
    #pragma unroll
    for (int off = 32; off > 0; off >>= 1) {
        empty += __shfl_xor(empty, off, 64);
        wnear += __shfl_xor(wnear, off, 64);
    }
    if (lane == 0 && ray_mask[r] != 0) {
        const int slot = r & (NBLK - 1);
        const float t = 1.0f - wnear;
        atomicAdd(&partials[slot],            empty);
        atomicAdd(&partials[NBLK + slot],     t * t);
        atomicAdd(&partials[2 * NBLK + slot], 1.0f);
    }
}

// Reduce [3*NBLK] partials with one wave (v4f loads).
__global__ void sight_finalize(const float* __restrict__ partials,
                               float* __restrict__ out)
{
    const int lane = threadIdx.x;          // 64 threads
    const v4f* p = (const v4f*)partials;   // each array = NBLK/4 = 256 v4f
    v4f e4 = {0,0,0,0}, n4 = {0,0,0,0}, m4 = {0,0,0,0};
    #pragma unroll
    for (int k = 0; k < NBLK / 4 / 64; ++k) {   // 4
        e4 += p[lane + 64 * k];
        n4 += p[256 + lane + 64 * k];
        m4 += p[512 + lane + 64 * k];
    }
    float e = e4.x + e4.y + e4.z + e4.w;
    float n = n4.x + n4.y + n4.z + n4.w;
    float m = m4.x + m4.y + m4.z + m4.w;
    #pragma unroll
    for (int off = 32; off > 0; off >>= 1) {
        e += __shfl_xor(e, off, 64);
        n += __shfl_xor(n, off, 64);
        m += __shfl_xor(m, off, 64);
    }
    if (lane == 0) {
        out[0] = e / m;   // loss_empty
        out[1] = n / m;   // loss_near
    }
}

extern "C" void kernel_launch(void* const* d_in, const int* in_sizes, int n_in,
                              void* d_out, int out_size, void* d_ws, size_t ws_size,
                              hipStream_t stream) {
    const float* ray_depth = (const float*)d_in[0];
    const float* z_vals    = (const float*)d_in[1];
    const float* weights   = (const float*)d_in[2];
    const int*   ray_mask  = (const int*)d_in[3];

    const int n_rays = in_sizes[0];                // ray_depth is [N,1]
    const int S      = in_sizes[1] / n_rays;       // 1024

    float* partials = (float*)d_ws;                // 3*NBLK floats = 12 KB

    if (S == 1024 && n_rays <= NW * 64) {
        // fused path writes every slot directly -- no memset needed
        sight_fused_1024<<<NBLK, 256, 0, stream>>>(
            ray_depth, z_vals, weights, ray_mask, partials, n_rays);
    } else {
        hipMemsetAsync(partials, 0, 3 * NBLK * sizeof(float), stream);
        const int blocks = (n_rays + 3) / 4;
        sight_near_loss_generic<<<blocks, 256, 0, stream>>>(
            ray_depth, z_vals, weights, ray_mask, partials, n_rays, S);
    }
    sight_finalize<<<1, 64, 0, stream>>>(partials, (float*)d_out);
}